// Round 10
// baseline (352.407 us; speedup 1.0000x reference)
//
#include <hip/hip_runtime.h>
#include <hip/hip_bf16.h>

// MultiHeadAttention: B=4, S=2048, D=1024, H=16, Dh=64. I/O fp32, compute bf16.
// R14b = R14 resubmitted verbatim (R9-round container acquisition failed, same
//   infra signature as R6; staging math re-audited - layout bijective, linear).
// R14 = R13 with GEMM BK 32->64: stage [128][64] tiles (32KB LDS), halving the
//   per-K-step barrier-drain count (32->16 rounds) and doubling the MFMA
//   cluster per drain (16->32/wave). Mechanism: at K=1024 the vmcnt(0) drain
//   at each barrier is the binding cost (gemm at 621 TF = the 2-barrier
//   ladder point; MfmaUtil 25%, all pipes idle). m132's BK=128 regressed via
//   64KB LDS occupancy loss - 32KB avoids that (still 5 blocks/CU, VGPR-capped).
// R13 carried: GEMM LDS dedup (neutral but harmless), flash XCD swizzle.
// R12 core: flash in-register P via swapped 32x32 QK^T + sigma permutation.
// Banned: single-barrier dbuf (R8, 3x regression on flash).
// Tripwire: gemm WRITE_SIZE must stay ~50MB (spill watch, VGPR ~100).

typedef __bf16 bf16_t;
typedef __attribute__((ext_vector_type(8))) __bf16 bf16x8;
typedef __attribute__((ext_vector_type(4))) __bf16 bf16x4;
typedef __attribute__((ext_vector_type(4))) float f32x4;
typedef __attribute__((ext_vector_type(16))) float f32x16;

#define MFMA(a, b, c) __builtin_amdgcn_mfma_f32_16x16x32_bf16((a), (b), (c), 0, 0, 0)
#define MFMA32(a, b, c) __builtin_amdgcn_mfma_f32_32x32x16_bf16((a), (b), (c), 0, 0, 0)

__device__ __forceinline__ float fast_exp2(float x) {
#if __has_builtin(__builtin_amdgcn_exp2f)
  return __builtin_amdgcn_exp2f(x);
#else
  return exp2f(x);
#endif
}

__device__ __forceinline__ bf16x8 load8_bf16(const bf16_t* p) {
  return *(const bf16x8*)p;
}
__device__ __forceinline__ bf16x8 load8_bf16(const float* p) {
  f32x4 a = *(const f32x4*)p;
  f32x4 b = *(const f32x4*)(p + 4);
  bf16x8 r;
  for (int i = 0; i < 4; ++i) { r[i] = (bf16_t)a[i]; r[i + 4] = (bf16_t)b[i]; }
  return r;
}

__device__ __forceinline__ void gload_lds16(const bf16_t* g, bf16_t* l) {
  __builtin_amdgcn_global_load_lds(
      (const __attribute__((address_space(1))) void*)g,
      (__attribute__((address_space(3))) void*)l, 16, 0, 0);
}

// ---------------- fp32 -> bf16 bulk convert ----------------
__global__ __launch_bounds__(256) void convert_bf16(
    const float* __restrict__ xq, const float* __restrict__ xk, const float* __restrict__ xv,
    const float* __restrict__ wq, const float* __restrict__ wk, const float* __restrict__ wv,
    const float* __restrict__ wo,
    bf16_t* __restrict__ xqb, bf16_t* __restrict__ xkb, bf16_t* __restrict__ xvb,
    bf16_t* __restrict__ wqb, bf16_t* __restrict__ wkb, bf16_t* __restrict__ wvb,
    bf16_t* __restrict__ wob) {
  const float* s;
  bf16_t* d;
  size_t n;
  switch (blockIdx.y) {
    case 0: s = xq; d = xqb; n = 8388608; break;
    case 1: s = xk; d = xkb; n = 8388608; break;
    case 2: s = xv; d = xvb; n = 8388608; break;
    case 3: s = wq; d = wqb; n = 1048576; break;
    case 4: s = wk; d = wkb; n = 1048576; break;
    case 5: s = wv; d = wvb; n = 1048576; break;
    default: s = wo; d = wob; n = 1048576; break;
  }
  size_t idx = ((size_t)blockIdx.x * 256 + threadIdx.x) * 8;
  if (idx < n) *(bf16x8*)&d[idx] = load8_bf16(&s[idx]);
}

// ---------------- GEMM: C[m,n] = (sum_k A[m,k]*W[n,k] + bias[n]) * sc --------
// M = grid.x*128, N = grid.y*128, K = 1024. Row-major, K contiguous (NT gemm).
// BK=64: [128][64] tiles, 16 staging rounds, 32 MFMA/wave/round.
// ASYNC: global_load_lds staging (requires TA=TW=bf16).
// VT: write per-head transposed Vt[((b*16+h)*64+d)*2048+s]. QS: scale output.
template <typename TA, typename TW, typename TC, bool VT, bool QS, bool ASYNC>
__device__ __forceinline__ void gemm_body(const TA* __restrict__ A,
                                          const TW* __restrict__ W,
                                          const float* __restrict__ bia,
                                          TC* __restrict__ C,
                                          bf16_t* sA, bf16_t* sW) {
  const int tid = threadIdx.x;
  const int lane = tid & 63;
  const int w = tid >> 6;
  const int ln = lane & 15;
  const int q = lane >> 4;
  const int wm = w >> 1, wn = w & 1;
  const size_t m0 = (size_t)blockIdx.x * 128;
  const size_t n0 = (size_t)blockIdx.y * 128;

  f32x4 zero = {0.f, 0.f, 0.f, 0.f};
  f32x4 acc[4][4];
  for (int i = 0; i < 4; ++i)
    for (int j = 0; j < 4; ++j) acc[i][j] = zero;

  for (int k0 = 0; k0 < 1024; k0 += 64) {
    if (ASYNC) {
      __syncthreads();  // previous round's LDS readers done
      // 1024 chunks of 16B per tile; wave-uniform dest + lane*16 (linear LDS)
      for (int i = 0; i < 4; ++i) {
        int c = w * 64 + i * 256 + lane;   // chunk 0..1023
        int row = c >> 3;                  // 0..127
        int k2 = (c & 7) * 8;              // 0..56
        gload_lds16((const bf16_t*)A + (m0 + row) * 1024 + k0 + k2,
                    &sA[(w * 64 + i * 256) * 8]);
        gload_lds16((const bf16_t*)W + (n0 + row) * 1024 + k0 + k2,
                    &sW[(w * 64 + i * 256) * 8]);
      }
      __syncthreads();  // vmcnt(0) drain before barrier completes staging
    } else {
      bf16x8 ar[4], wr[4];
      for (int i = 0; i < 4; ++i) {
        int c = tid + 256 * i;
        int row = c >> 3;
        int ko = (c & 7) * 8;
        ar[i] = load8_bf16(&A[(m0 + row) * 1024 + k0 + ko]);
        wr[i] = load8_bf16(&W[(n0 + row) * 1024 + k0 + ko]);
      }
      __syncthreads();
      for (int i = 0; i < 4; ++i) {
        int c = tid + 256 * i;
        *(bf16x8*)&sA[c * 8] = ar[i];
        *(bf16x8*)&sW[c * 8] = wr[i];
      }
      __syncthreads();
    }

    for (int kk = 0; kk < 2; ++kk) {
      bf16x8 af[4], bfr[4];
      for (int t = 0; t < 4; ++t)
        af[t] = *(const bf16x8*)&sA[(wm * 64 + t * 16 + ln) * 64 + kk * 32 + q * 8];
      for (int t = 0; t < 4; ++t)
        bfr[t] = *(const bf16x8*)&sW[(wn * 64 + t * 16 + ln) * 64 + kk * 32 + q * 8];
      for (int tm = 0; tm < 4; ++tm)
        for (int tn = 0; tn < 4; ++tn)
          acc[tm][tn] = MFMA(af[tm], bfr[tn], acc[tm][tn]);
    }
  }

  const float sc = QS ? 0.180336880f : 1.0f;  // 0.125 * log2(e)
  for (int tn = 0; tn < 4; ++tn) {
    size_t gc = n0 + wn * 64 + tn * 16 + ln;
    float bv = bia[gc];
    for (int tm = 0; tm < 4; ++tm) {
      size_t gr0 = m0 + wm * 64 + tm * 16 + q * 4;
      if (VT) {
        size_t bidx = gr0 >> 11, s0 = gr0 & 2047;
        size_t h = gc >> 6, d = gc & 63;
        bf16x4 pk;
        for (int r = 0; r < 4; ++r) pk[r] = (bf16_t)(acc[tm][tn][r] + bv);
        *(bf16x4*)&((bf16_t*)C)[((bidx * 16 + h) * 64 + d) * 2048 + s0] = pk;
      } else {
        for (int r = 0; r < 4; ++r) {
          float v = (acc[tm][tn][r] + bv) * sc;
          C[(gr0 + r) * 1024 + gc] = (TC)v;
        }
      }
    }
  }
}

// bf16 fast path (ASYNC staging); ONE shared pair for all three branch arms
__global__ __launch_bounds__(256) void gemm_qkv_b(
    const bf16_t* __restrict__ Xq, const bf16_t* __restrict__ Xk, const bf16_t* __restrict__ Xv,
    const bf16_t* __restrict__ Wq, const bf16_t* __restrict__ Wk, const bf16_t* __restrict__ Wv,
    const float* __restrict__ Bq, const float* __restrict__ Bk, const float* __restrict__ Bv,
    bf16_t* __restrict__ Oq, bf16_t* __restrict__ Ok, bf16_t* __restrict__ Ov) {
  __shared__ __align__(16) bf16_t sA[128 * 64];
  __shared__ __align__(16) bf16_t sW[128 * 64];
  if (blockIdx.z == 0)      gemm_body<bf16_t, bf16_t, bf16_t, false, true , true>(Xq, Wq, Bq, Oq, sA, sW);
  else if (blockIdx.z == 1) gemm_body<bf16_t, bf16_t, bf16_t, false, false, true>(Xk, Wk, Bk, Ok, sA, sW);
  else                      gemm_body<bf16_t, bf16_t, bf16_t, true , false, true>(Xv, Wv, Bv, Ov, sA, sW);
}
__global__ __launch_bounds__(256) void gemm_out_b(
    const bf16_t* __restrict__ A, const bf16_t* __restrict__ W,
    const float* __restrict__ bia, float* __restrict__ C) {
  __shared__ __align__(16) bf16_t sA[128 * 64];
  __shared__ __align__(16) bf16_t sW[128 * 64];
  gemm_body<bf16_t, bf16_t, float, false, false, true>(A, W, bia, C, sA, sW);
}

// fp32-input fallback (register staging + fused convert)
__global__ __launch_bounds__(256) void gemm_qkv_f(
    const float* __restrict__ Xq, const float* __restrict__ Xk, const float* __restrict__ Xv,
    const float* __restrict__ Wq, const float* __restrict__ Wk, const float* __restrict__ Wv,
    const float* __restrict__ Bq, const float* __restrict__ Bk, const float* __restrict__ Bv,
    bf16_t* __restrict__ Oq, bf16_t* __restrict__ Ok, bf16_t* __restrict__ Ov) {
  __shared__ __align__(16) bf16_t sA[128 * 64];
  __shared__ __align__(16) bf16_t sW[128 * 64];
  if (blockIdx.z == 0)      gemm_body<float, float, bf16_t, false, true , false>(Xq, Wq, Bq, Oq, sA, sW);
  else if (blockIdx.z == 1) gemm_body<float, float, bf16_t, false, false, false>(Xk, Wk, Bk, Ok, sA, sW);
  else                      gemm_body<float, float, bf16_t, true , false, false>(Xv, Wv, Bv, Ov, sA, sW);
}
__global__ __launch_bounds__(256) void gemm_out_f(
    const bf16_t* __restrict__ A, const float* __restrict__ W,
    const float* __restrict__ bia, float* __restrict__ C) {
  __shared__ __align__(16) bf16_t sA[128 * 64];
  __shared__ __align__(16) bf16_t sW[128 * 64];
  gemm_body<bf16_t, float, float, false, false, false>(A, W, bia, C, sA, sW);
}

// ---------------- Flash attention (unnormalized exp2 softmax) ----------------
// Q pre-scaled by 0.125*log2e; K in [B*S,1024]; Vt in [b][h][64][2048].
// R12 core: 512 threads (8 waves); BR=256 (wave w owns q-rows w*32..w*32+31);
// BC=64 keys/iter; grid = (8, 64) = 2 blocks/CU. 32x32x16 MFMA, swapped QK^T;
// sigma k-slot permutation -> PV A-frag = lane's own p-regs, V B-frag via
// two ds_read_b64 (+4hi, +8+4hi). R13: XCD-chunked block swizzle (8 heads/XCD).
__global__ __launch_bounds__(512, 4) void flash_attn(const bf16_t* __restrict__ Q,
                                                     const bf16_t* __restrict__ K,
                                                     const bf16_t* __restrict__ Vt,
                                                     bf16_t* __restrict__ O) {
  __shared__ __align__(16) bf16_t sQ[256 * 68];   // Q staging
  __shared__ __align__(16) bf16_t sK[64 * 68];    // [key][d]
  __shared__ __align__(16) bf16_t sVt[64 * 68];   // [d][key]
  __shared__ __align__(16) float sL[256];         // row sums (per-wave strips)

  const int tid = threadIdx.x;
  const int lane = tid & 63;
  const int w = tid >> 6;          // 0..7
  const int c = lane & 31;
  const int hi = lane >> 5;

  // XCD-chunked bijective swizzle: nwg=512, 8 XCDs, chunk=64.
  // XCD x gets bh in [8x, 8x+8) -> K/V working set 8*512KB = 4MB = one L2.
  const int id = (int)blockIdx.x + 8 * (int)blockIdx.y;  // 0..511
  const int id2 = (id & 7) * 64 + (id >> 3);
  const int bh = id2 >> 3;
  const int q0 = (id2 & 7) * 256;
  const int b = bh >> 4;
  const int h = bh & 15;

  const bf16_t* Qb = Q + ((size_t)b * 2048 + q0) * 1024 + h * 64;
  const bf16_t* Kb = K + ((size_t)b * 2048) * 1024 + h * 64;
  const bf16_t* VtB = Vt + (size_t)bh * 64 * 2048;

  const int krow = tid >> 3;           // 0..63 (512 thr = 64 rows x 8 chunks)
  const int koff = (tid & 7) * 8;

  // prologue: prefetch K/V tile 0 (latency covered by Q staging + barrier)
  bf16x8 kreg = *(const bf16x8*)&Kb[(size_t)krow * 1024 + koff];
  bf16x8 vreg = *(const bf16x8*)&VtB[(size_t)krow * 2048 + koff];

  // stage Q tile [256][64]
  for (int i = 0; i < 4; ++i) {
    int cc = tid + 512 * i;       // 0..2047
    int row = cc >> 3;            // 0..255
    int off = (cc & 7) * 8;
    *(bf16x8*)&sQ[row * 68 + off] = *(const bf16x8*)&Qb[(size_t)row * 1024 + off];
  }
  __syncthreads();
  // Q B-frags: lane (hi,c) supplies col=qrow(w*32+c), k=d=ck*16+hi*8+e
  bf16x8 qf[4];
#pragma unroll
  for (int ck = 0; ck < 4; ++ck)
    qf[ck] = *(const bf16x8*)&sQ[(w * 32 + c) * 68 + ck * 16 + hi * 8];

  f32x16 oacc[2];
#pragma unroll
  for (int dt = 0; dt < 2; ++dt)
#pragma unroll
    for (int r = 0; r < 16; ++r) oacc[dt][r] = 0.f;
  float lpart = 0.f;

  for (int j0 = 0; j0 < 2048; j0 += 64) {
    __syncthreads();  // barrier A: prev readers done; prefetch vmcnt drains here
    *(bf16x8*)&sK[krow * 68 + koff] = kreg;
    *(bf16x8*)&sVt[krow * 68 + koff] = vreg;
    __syncthreads();  // barrier B: staging visible to all waves

    // prefetch NEXT tile (after barrier B); QK^T+softmax+PV covers the latency.
    if (j0 + 64 < 2048) {
      kreg = *(const bf16x8*)&Kb[(size_t)(j0 + 64 + krow) * 1024 + koff];
      vreg = *(const bf16x8*)&VtB[(size_t)krow * 2048 + (j0 + 64) + koff];
    }

    // S^T = K Q^T: A = K[32 keys][16 d-chunk], B = Q (qf). 2 key-tiles.
    f32x16 sacc[2];
#pragma unroll
    for (int kt = 0; kt < 2; ++kt)
#pragma unroll
      for (int r = 0; r < 16; ++r) sacc[kt][r] = 0.f;
#pragma unroll
    for (int ck = 0; ck < 4; ++ck) {
#pragma unroll
      for (int kt = 0; kt < 2; ++kt) {
        bf16x8 kf = *(const bf16x8*)&sK[(kt * 32 + c) * 68 + ck * 16 + hi * 8];
        sacc[kt] = MFMA32(kf, qf[ck], sacc[kt]);
      }
    }

    // softmax (exp2 domain) + PV, all in registers
#pragma unroll
    for (int kt = 0; kt < 2; ++kt) {
      float pe[16];
#pragma unroll
      for (int r = 0; r < 16; ++r) {
        pe[r] = fast_exp2(sacc[kt][r]);
        lpart += pe[r];
      }
      bf16x8 pa[2];  // A-frags: chunk kc=0 <- regs 0..7, kc=1 <- regs 8..15
#pragma unroll
      for (int e = 0; e < 8; ++e) {
        pa[0][e] = (bf16_t)pe[e];
        pa[1][e] = (bf16_t)pe[8 + e];
      }
#pragma unroll
      for (int kc = 0; kc < 2; ++kc) {
#pragma unroll
        for (int dt = 0; dt < 2; ++dt) {
          // V B-frag with sigma: keys kt*32+kc*16 + {4hi..4hi+3, 8+4hi..8+4hi+3}
          const bf16_t* vb = &sVt[(dt * 32 + c) * 68 + kt * 32 + kc * 16 + 4 * hi];
          bf16x4 v0 = *(const bf16x4*)vb;
          bf16x4 v1 = *(const bf16x4*)(vb + 8);
          bf16x8 vf = {v0[0], v0[1], v0[2], v0[3], v1[0], v1[1], v1[2], v1[3]};
          oacc[dt] = MFMA32(pa[kc], vf, oacc[dt]);
        }
      }
    }
  }

  // row sums: this lane covered 32 keys of qrow c; partner (lane^32) the rest
  lpart += __shfl_xor(lpart, 32);
  if (hi == 0) sL[w * 32 + c] = lpart;  // wave-private strip; lgkm orders

  // epilogue: O C-layout row = 8*bb + 4*hi + j; broadcast-read sums
  f32x4 linv[4];
#pragma unroll
  for (int bb = 0; bb < 4; ++bb) {
    f32x4 ls = *(const f32x4*)&sL[w * 32 + 8 * bb + 4 * hi];
#pragma unroll
    for (int j = 0; j < 4; ++j) linv[bb][j] = 1.f / ls[j];
  }
  bf16_t* Ob = O + ((size_t)b * 2048 + q0 + w * 32) * 1024 + h * 64;
#pragma unroll
  for (int dt = 0; dt < 2; ++dt)
#pragma unroll
    for (int bb = 0; bb < 4; ++bb)
#pragma unroll
      for (int j = 0; j < 4; ++j)
        Ob[(size_t)(8 * bb + 4 * hi + j) * 1024 + dt * 32 + c] =
            (bf16_t)(oacc[dt][4 * bb + j] * linv[bb][j]);
}

// ---------------- launch ----------------
extern "C" void kernel_launch(void* const* d_in, const int* in_sizes, int n_in,
                              void* d_out, int out_size, void* d_ws, size_t ws_size,
                              hipStream_t stream) {
  (void)in_sizes; (void)n_in; (void)out_size;
  const float* query = (const float*)d_in[0];
  const float* key   = (const float*)d_in[1];
  const float* value = (const float*)d_in[2];
  const float* Wq = (const float*)d_in[3];
  const float* bq = (const float*)d_in[4];
  const float* Wk = (const float*)d_in[5];
  const float* bk = (const float*)d_in[6];
  const float* Wv = (const float*)d_in[7];
  const float* bv = (const float*)d_in[8];
  const float* Wo = (const float*)d_in[9];
  const float* bo = (const float*)d_in[10];
  float* out = (float*)d_out;

  const size_t MD = (size_t)8192 * 1024;   // X elements
  const size_t WD = (size_t)1024 * 1024;   // W elements
  bf16_t* base = (bf16_t*)d_ws;
  bf16_t* Qw  = base;
  bf16_t* Kw  = Qw + MD;
  bf16_t* Vtw = Kw + MD;   // [b][h][64][2048]

  dim3 b256(256), b512(512);
  if (ws_size >= (6 * MD + 4 * WD) * sizeof(bf16_t)) {
    // fast path: pre-convert to bf16, async-staged GEMMs
    bf16_t* XqB = Vtw + MD;  // also reused as AO after gemm_qkv
    bf16_t* XkB = XqB + MD;
    bf16_t* XvB = XkB + MD;
    bf16_t* WqB = XvB + MD;
    bf16_t* WkB = WqB + WD;
    bf16_t* WvB = WkB + WD;
    bf16_t* WoB = WvB + WD;
    bf16_t* AO  = XqB;       // alias: XqB dead after gemm_qkv

    convert_bf16<<<dim3(4096, 7), b256, 0, stream>>>(
        query, key, value, Wq, Wk, Wv, Wo,
        XqB, XkB, XvB, WqB, WkB, WvB, WoB);
    gemm_qkv_b<<<dim3(64, 8, 3), b256, 0, stream>>>(
        XqB, XkB, XvB, WqB, WkB, WvB, bq, bk, bv, Qw, Kw, Vtw);
    flash_attn<<<dim3(8, 64), b512, 0, stream>>>(Qw, Kw, Vtw, AO);
    gemm_out_b<<<dim3(64, 8), b256, 0, stream>>>(AO, WoB, bo, out);
  } else {
    // fallback: fused-convert GEMMs (needs 64 MB ws)
    bf16_t* AO = Vtw + MD;
    gemm_qkv_f<<<dim3(64, 8, 3), b256, 0, stream>>>(
        query, key, value, Wq, Wk, Wv, bq, bk, bv, Qw, Kw, Vtw);
    flash_attn<<<dim3(8, 64), b512, 0, stream>>>(Qw, Kw, Vtw, AO);
    gemm_out_f<<<dim3(64, 8), b256, 0, stream>>>(AO, Wo, bo, out);
  }
}

// Round 11
// 324.426 us; speedup vs baseline: 1.0862x; 1.0862x over previous
//
#include <hip/hip_runtime.h>
#include <hip/hip_bf16.h>

// MultiHeadAttention: B=4, S=2048, D=1024, H=16, Dh=64. I/O fp32, compute bf16.
// R15 = R14b + sigma-XOR LDS swizzle on the BK=64 GEMM tiles.
//   R14b post-mortem: BK=64 made row stride 128B = 32 banks -> all 16 lanes of
//   each ds_read_b128 start in the SAME bank (guide G4 case); BANK_CONFLICT
//   tripled 6.3M->18.9M and ate the drain-halving gain (83->90us).
//   Fix (rule #21 both-sides-or-neither): gload_lds dest stays LINEAR; the
//   per-lane GLOBAL source is permuted so slot (row,j) holds k-chunk
//   j^(row&7); fragment reads fetch chunk jg at slot jg^(row&7). Involution.
//   Read banks: (jg^(ln&7))*16B -> 8 distinct slots = 32 banks covered,
//   2-way alias only (free). Coalescing unchanged (permute within 128B row).
// Carried: R13 LDS dedup + flash XCD swizzle; R12 flash in-register P.
// Banned: single-barrier dbuf (R8). Tripwires: gemm WRITE ~49MB, absmax same.

typedef __bf16 bf16_t;
typedef __attribute__((ext_vector_type(8))) __bf16 bf16x8;
typedef __attribute__((ext_vector_type(4))) __bf16 bf16x4;
typedef __attribute__((ext_vector_type(4))) float f32x4;
typedef __attribute__((ext_vector_type(16))) float f32x16;

#define MFMA(a, b, c) __builtin_amdgcn_mfma_f32_16x16x32_bf16((a), (b), (c), 0, 0, 0)
#define MFMA32(a, b, c) __builtin_amdgcn_mfma_f32_32x32x16_bf16((a), (b), (c), 0, 0, 0)

__device__ __forceinline__ float fast_exp2(float x) {
#if __has_builtin(__builtin_amdgcn_exp2f)
  return __builtin_amdgcn_exp2f(x);
#else
  return exp2f(x);
#endif
}

__device__ __forceinline__ bf16x8 load8_bf16(const bf16_t* p) {
  return *(const bf16x8*)p;
}
__device__ __forceinline__ bf16x8 load8_bf16(const float* p) {
  f32x4 a = *(const f32x4*)p;
  f32x4 b = *(const f32x4*)(p + 4);
  bf16x8 r;
  for (int i = 0; i < 4; ++i) { r[i] = (bf16_t)a[i]; r[i + 4] = (bf16_t)b[i]; }
  return r;
}

__device__ __forceinline__ void gload_lds16(const bf16_t* g, bf16_t* l) {
  __builtin_amdgcn_global_load_lds(
      (const __attribute__((address_space(1))) void*)g,
      (__attribute__((address_space(3))) void*)l, 16, 0, 0);
}

// ---------------- fp32 -> bf16 bulk convert ----------------
__global__ __launch_bounds__(256) void convert_bf16(
    const float* __restrict__ xq, const float* __restrict__ xk, const float* __restrict__ xv,
    const float* __restrict__ wq, const float* __restrict__ wk, const float* __restrict__ wv,
    const float* __restrict__ wo,
    bf16_t* __restrict__ xqb, bf16_t* __restrict__ xkb, bf16_t* __restrict__ xvb,
    bf16_t* __restrict__ wqb, bf16_t* __restrict__ wkb, bf16_t* __restrict__ wvb,
    bf16_t* __restrict__ wob) {
  const float* s;
  bf16_t* d;
  size_t n;
  switch (blockIdx.y) {
    case 0: s = xq; d = xqb; n = 8388608; break;
    case 1: s = xk; d = xkb; n = 8388608; break;
    case 2: s = xv; d = xvb; n = 8388608; break;
    case 3: s = wq; d = wqb; n = 1048576; break;
    case 4: s = wk; d = wkb; n = 1048576; break;
    case 5: s = wv; d = wvb; n = 1048576; break;
    default: s = wo; d = wob; n = 1048576; break;
  }
  size_t idx = ((size_t)blockIdx.x * 256 + threadIdx.x) * 8;
  if (idx < n) *(bf16x8*)&d[idx] = load8_bf16(&s[idx]);
}

// ---------------- GEMM: C[m,n] = (sum_k A[m,k]*W[n,k] + bias[n]) * sc --------
// M = grid.x*128, N = grid.y*128, K = 1024. Row-major, K contiguous (NT gemm).
// BK=64: [128][64] tiles, 16 staging rounds, 32 MFMA/wave/round.
// sigma-XOR swizzle: LDS slot (row, j) holds global k-chunk j^(row&7).
// ASYNC: global_load_lds staging (linear dest, permuted per-lane source).
// VT: write per-head transposed Vt[((b*16+h)*64+d)*2048+s]. QS: scale output.
template <typename TA, typename TW, typename TC, bool VT, bool QS, bool ASYNC>
__device__ __forceinline__ void gemm_body(const TA* __restrict__ A,
                                          const TW* __restrict__ W,
                                          const float* __restrict__ bia,
                                          TC* __restrict__ C,
                                          bf16_t* sA, bf16_t* sW) {
  const int tid = threadIdx.x;
  const int lane = tid & 63;
  const int w = tid >> 6;
  const int ln = lane & 15;
  const int q = lane >> 4;
  const int wm = w >> 1, wn = w & 1;
  const size_t m0 = (size_t)blockIdx.x * 128;
  const size_t n0 = (size_t)blockIdx.y * 128;

  f32x4 zero = {0.f, 0.f, 0.f, 0.f};
  f32x4 acc[4][4];
  for (int i = 0; i < 4; ++i)
    for (int j = 0; j < 4; ++j) acc[i][j] = zero;

  for (int k0 = 0; k0 < 1024; k0 += 64) {
    if (ASYNC) {
      __syncthreads();  // previous round's LDS readers done
      // 1024 slots of 16B/tile; LINEAR dest (slot c at byte c*16), per-lane
      // global source swizzled: slot (row,j) <- global chunk j^(row&7).
      for (int i = 0; i < 4; ++i) {
        int c = w * 64 + i * 256 + lane;   // slot 0..1023
        int row = c >> 3;                  // 0..127
        int j = c & 7;
        int k2 = (j ^ (row & 7)) * 8;      // swizzled global k-chunk
        gload_lds16((const bf16_t*)A + (m0 + row) * 1024 + k0 + k2,
                    &sA[(w * 64 + i * 256) * 8]);
        gload_lds16((const bf16_t*)W + (n0 + row) * 1024 + k0 + k2,
                    &sW[(w * 64 + i * 256) * 8]);
      }
      __syncthreads();  // vmcnt(0) drain before barrier completes staging
    } else {
      bf16x8 ar[4], wr[4];
      for (int i = 0; i < 4; ++i) {
        int c = tid + 256 * i;
        int row = c >> 3;
        int j = c & 7;
        int ko = (j ^ (row & 7)) * 8;      // same slot->chunk mapping
        ar[i] = load8_bf16(&A[(m0 + row) * 1024 + k0 + ko]);
        wr[i] = load8_bf16(&W[(n0 + row) * 1024 + k0 + ko]);
      }
      __syncthreads();
      for (int i = 0; i < 4; ++i) {
        int c = tid + 256 * i;
        *(bf16x8*)&sA[c * 8] = ar[i];
        *(bf16x8*)&sW[c * 8] = wr[i];
      }
      __syncthreads();
    }

    for (int kk = 0; kk < 2; ++kk) {
      const int jg = kk * 4 + q;           // global k-chunk 0..7
      bf16x8 af[4], bfr[4];
      for (int t = 0; t < 4; ++t) {
        int row = wm * 64 + t * 16 + ln;
        af[t] = *(const bf16x8*)&sA[row * 64 + ((jg ^ (row & 7)) * 8)];
      }
      for (int t = 0; t < 4; ++t) {
        int row = wn * 64 + t * 16 + ln;
        bfr[t] = *(const bf16x8*)&sW[row * 64 + ((jg ^ (row & 7)) * 8)];
      }
      for (int tm = 0; tm < 4; ++tm)
        for (int tn = 0; tn < 4; ++tn)
          acc[tm][tn] = MFMA(af[tm], bfr[tn], acc[tm][tn]);
    }
  }

  const float sc = QS ? 0.180336880f : 1.0f;  // 0.125 * log2(e)
  for (int tn = 0; tn < 4; ++tn) {
    size_t gc = n0 + wn * 64 + tn * 16 + ln;
    float bv = bia[gc];
    for (int tm = 0; tm < 4; ++tm) {
      size_t gr0 = m0 + wm * 64 + tm * 16 + q * 4;
      if (VT) {
        size_t bidx = gr0 >> 11, s0 = gr0 & 2047;
        size_t h = gc >> 6, d = gc & 63;
        bf16x4 pk;
        for (int r = 0; r < 4; ++r) pk[r] = (bf16_t)(acc[tm][tn][r] + bv);
        *(bf16x4*)&((bf16_t*)C)[((bidx * 16 + h) * 64 + d) * 2048 + s0] = pk;
      } else {
        for (int r = 0; r < 4; ++r) {
          float v = (acc[tm][tn][r] + bv) * sc;
          C[(gr0 + r) * 1024 + gc] = (TC)v;
        }
      }
    }
  }
}

// bf16 fast path (ASYNC staging); ONE shared pair for all three branch arms
__global__ __launch_bounds__(256) void gemm_qkv_b(
    const bf16_t* __restrict__ Xq, const bf16_t* __restrict__ Xk, const bf16_t* __restrict__ Xv,
    const bf16_t* __restrict__ Wq, const bf16_t* __restrict__ Wk, const bf16_t* __restrict__ Wv,
    const float* __restrict__ Bq, const float* __restrict__ Bk, const float* __restrict__ Bv,
    bf16_t* __restrict__ Oq, bf16_t* __restrict__ Ok, bf16_t* __restrict__ Ov) {
  __shared__ __align__(16) bf16_t sA[128 * 64];
  __shared__ __align__(16) bf16_t sW[128 * 64];
  if (blockIdx.z == 0)      gemm_body<bf16_t, bf16_t, bf16_t, false, true , true>(Xq, Wq, Bq, Oq, sA, sW);
  else if (blockIdx.z == 1) gemm_body<bf16_t, bf16_t, bf16_t, false, false, true>(Xk, Wk, Bk, Ok, sA, sW);
  else                      gemm_body<bf16_t, bf16_t, bf16_t, true , false, true>(Xv, Wv, Bv, Ov, sA, sW);
}
__global__ __launch_bounds__(256) void gemm_out_b(
    const bf16_t* __restrict__ A, const bf16_t* __restrict__ W,
    const float* __restrict__ bia, float* __restrict__ C) {
  __shared__ __align__(16) bf16_t sA[128 * 64];
  __shared__ __align__(16) bf16_t sW[128 * 64];
  gemm_body<bf16_t, bf16_t, float, false, false, true>(A, W, bia, C, sA, sW);
}

// fp32-input fallback (register staging + fused convert)
__global__ __launch_bounds__(256) void gemm_qkv_f(
    const float* __restrict__ Xq, const float* __restrict__ Xk, const float* __restrict__ Xv,
    const float* __restrict__ Wq, const float* __restrict__ Wk, const float* __restrict__ Wv,
    const float* __restrict__ Bq, const float* __restrict__ Bk, const float* __restrict__ Bv,
    bf16_t* __restrict__ Oq, bf16_t* __restrict__ Ok, bf16_t* __restrict__ Ov) {
  __shared__ __align__(16) bf16_t sA[128 * 64];
  __shared__ __align__(16) bf16_t sW[128 * 64];
  if (blockIdx.z == 0)      gemm_body<float, float, bf16_t, false, true , false>(Xq, Wq, Bq, Oq, sA, sW);
  else if (blockIdx.z == 1) gemm_body<float, float, bf16_t, false, false, false>(Xk, Wk, Bk, Ok, sA, sW);
  else                      gemm_body<float, float, bf16_t, true , false, false>(Xv, Wv, Bv, Ov, sA, sW);
}
__global__ __launch_bounds__(256) void gemm_out_f(
    const bf16_t* __restrict__ A, const float* __restrict__ W,
    const float* __restrict__ bia, float* __restrict__ C) {
  __shared__ __align__(16) bf16_t sA[128 * 64];
  __shared__ __align__(16) bf16_t sW[128 * 64];
  gemm_body<bf16_t, float, float, false, false, false>(A, W, bia, C, sA, sW);
}

// ---------------- Flash attention (unnormalized exp2 softmax) ----------------
// Q pre-scaled by 0.125*log2e; K in [B*S,1024]; Vt in [b][h][64][2048].
// R12 core: 512 threads (8 waves); BR=256 (wave w owns q-rows w*32..w*32+31);
// BC=64 keys/iter; grid = (8, 64) = 2 blocks/CU. 32x32x16 MFMA, swapped QK^T;
// sigma k-slot permutation -> PV A-frag = lane's own p-regs, V B-frag via
// two ds_read_b64 (+4hi, +8+4hi). R13: XCD-chunked block swizzle (8 heads/XCD).
__global__ __launch_bounds__(512, 4) void flash_attn(const bf16_t* __restrict__ Q,
                                                     const bf16_t* __restrict__ K,
                                                     const bf16_t* __restrict__ Vt,
                                                     bf16_t* __restrict__ O) {
  __shared__ __align__(16) bf16_t sQ[256 * 68];   // Q staging
  __shared__ __align__(16) bf16_t sK[64 * 68];    // [key][d]
  __shared__ __align__(16) bf16_t sVt[64 * 68];   // [d][key]
  __shared__ __align__(16) float sL[256];         // row sums (per-wave strips)

  const int tid = threadIdx.x;
  const int lane = tid & 63;
  const int w = tid >> 6;          // 0..7
  const int c = lane & 31;
  const int hi = lane >> 5;

  // XCD-chunked bijective swizzle: nwg=512, 8 XCDs, chunk=64.
  // XCD x gets bh in [8x, 8x+8) -> K/V working set 8*512KB = 4MB = one L2.
  const int id = (int)blockIdx.x + 8 * (int)blockIdx.y;  // 0..511
  const int id2 = (id & 7) * 64 + (id >> 3);
  const int bh = id2 >> 3;
  const int q0 = (id2 & 7) * 256;
  const int b = bh >> 4;
  const int h = bh & 15;

  const bf16_t* Qb = Q + ((size_t)b * 2048 + q0) * 1024 + h * 64;
  const bf16_t* Kb = K + ((size_t)b * 2048) * 1024 + h * 64;
  const bf16_t* VtB = Vt + (size_t)bh * 64 * 2048;

  const int krow = tid >> 3;           // 0..63 (512 thr = 64 rows x 8 chunks)
  const int koff = (tid & 7) * 8;

  // prologue: prefetch K/V tile 0 (latency covered by Q staging + barrier)
  bf16x8 kreg = *(const bf16x8*)&Kb[(size_t)krow * 1024 + koff];
  bf16x8 vreg = *(const bf16x8*)&VtB[(size_t)krow * 2048 + koff];

  // stage Q tile [256][64]
  for (int i = 0; i < 4; ++i) {
    int cc = tid + 512 * i;       // 0..2047
    int row = cc >> 3;            // 0..255
    int off = (cc & 7) * 8;
    *(bf16x8*)&sQ[row * 68 + off] = *(const bf16x8*)&Qb[(size_t)row * 1024 + off];
  }
  __syncthreads();
  // Q B-frags: lane (hi,c) supplies col=qrow(w*32+c), k=d=ck*16+hi*8+e
  bf16x8 qf[4];
#pragma unroll
  for (int ck = 0; ck < 4; ++ck)
    qf[ck] = *(const bf16x8*)&sQ[(w * 32 + c) * 68 + ck * 16 + hi * 8];

  f32x16 oacc[2];
#pragma unroll
  for (int dt = 0; dt < 2; ++dt)
#pragma unroll
    for (int r = 0; r < 16; ++r) oacc[dt][r] = 0.f;
  float lpart = 0.f;

  for (int j0 = 0; j0 < 2048; j0 += 64) {
    __syncthreads();  // barrier A: prev readers done; prefetch vmcnt drains here
    *(bf16x8*)&sK[krow * 68 + koff] = kreg;
    *(bf16x8*)&sVt[krow * 68 + koff] = vreg;
    __syncthreads();  // barrier B: staging visible to all waves

    // prefetch NEXT tile (after barrier B); QK^T+softmax+PV covers the latency.
    if (j0 + 64 < 2048) {
      kreg = *(const bf16x8*)&Kb[(size_t)(j0 + 64 + krow) * 1024 + koff];
      vreg = *(const bf16x8*)&VtB[(size_t)krow * 2048 + (j0 + 64) + koff];
    }

    // S^T = K Q^T: A = K[32 keys][16 d-chunk], B = Q (qf). 2 key-tiles.
    f32x16 sacc[2];
#pragma unroll
    for (int kt = 0; kt < 2; ++kt)
#pragma unroll
      for (int r = 0; r < 16; ++r) sacc[kt][r] = 0.f;
#pragma unroll
    for (int ck = 0; ck < 4; ++ck) {
#pragma unroll
      for (int kt = 0; kt < 2; ++kt) {
        bf16x8 kf = *(const bf16x8*)&sK[(kt * 32 + c) * 68 + ck * 16 + hi * 8];
        sacc[kt] = MFMA32(kf, qf[ck], sacc[kt]);
      }
    }

    // softmax (exp2 domain) + PV, all in registers
#pragma unroll
    for (int kt = 0; kt < 2; ++kt) {
      float pe[16];
#pragma unroll
      for (int r = 0; r < 16; ++r) {
        pe[r] = fast_exp2(sacc[kt][r]);
        lpart += pe[r];
      }
      bf16x8 pa[2];  // A-frags: chunk kc=0 <- regs 0..7, kc=1 <- regs 8..15
#pragma unroll
      for (int e = 0; e < 8; ++e) {
        pa[0][e] = (bf16_t)pe[e];
        pa[1][e] = (bf16_t)pe[8 + e];
      }
#pragma unroll
      for (int kc = 0; kc < 2; ++kc) {
#pragma unroll
        for (int dt = 0; dt < 2; ++dt) {
          // V B-frag with sigma: keys kt*32+kc*16 + {4hi..4hi+3, 8+4hi..8+4hi+3}
          const bf16_t* vb = &sVt[(dt * 32 + c) * 68 + kt * 32 + kc * 16 + 4 * hi];
          bf16x4 v0 = *(const bf16x4*)vb;
          bf16x4 v1 = *(const bf16x4*)(vb + 8);
          bf16x8 vf = {v0[0], v0[1], v0[2], v0[3], v1[0], v1[1], v1[2], v1[3]};
          oacc[dt] = MFMA32(pa[kc], vf, oacc[dt]);
        }
      }
    }
  }

  // row sums: this lane covered 32 keys of qrow c; partner (lane^32) the rest
  lpart += __shfl_xor(lpart, 32);
  if (hi == 0) sL[w * 32 + c] = lpart;  // wave-private strip; lgkm orders

  // epilogue: O C-layout row = 8*bb + 4*hi + j; broadcast-read sums
  f32x4 linv[4];
#pragma unroll
  for (int bb = 0; bb < 4; ++bb) {
    f32x4 ls = *(const f32x4*)&sL[w * 32 + 8 * bb + 4 * hi];
#pragma unroll
    for (int j = 0; j < 4; ++j) linv[bb][j] = 1.f / ls[j];
  }
  bf16_t* Ob = O + ((size_t)b * 2048 + q0 + w * 32) * 1024 + h * 64;
#pragma unroll
  for (int dt = 0; dt < 2; ++dt)
#pragma unroll
    for (int bb = 0; bb < 4; ++bb)
#pragma unroll
      for (int j = 0; j < 4; ++j)
        Ob[(size_t)(8 * bb + 4 * hi + j) * 1024 + dt * 32 + c] =
            (bf16_t)(oacc[dt][4 * bb + j] * linv[bb][j]);
}

// ---------------- launch ----------------
extern "C" void kernel_launch(void* const* d_in, const int* in_sizes, int n_in,
                              void* d_out, int out_size, void* d_ws, size_t ws_size,
                              hipStream_t stream) {
  (void)in_sizes; (void)n_in; (void)out_size;
  const float* query = (const float*)d_in[0];
  const float* key   = (const float*)d_in[1];
  const float* value = (const float*)d_in[2];
  const float* Wq = (const float*)d_in[3];
  const float* bq = (const float*)d_in[4];
  const float* Wk = (const float*)d_in[5];
  const float* bk = (const float*)d_in[6];
  const float* Wv = (const float*)d_in[7];
  const float* bv = (const float*)d_in[8];
  const float* Wo = (const float*)d_in[9];
  const float* bo = (const float*)d_in[10];
  float* out = (float*)d_out;

  const size_t MD = (size_t)8192 * 1024;   // X elements
  const size_t WD = (size_t)1024 * 1024;   // W elements
  bf16_t* base = (bf16_t*)d_ws;
  bf16_t* Qw  = base;
  bf16_t* Kw  = Qw + MD;
  bf16_t* Vtw = Kw + MD;   // [b][h][64][2048]

  dim3 b256(256), b512(512);
  if (ws_size >= (6 * MD + 4 * WD) * sizeof(bf16_t)) {
    // fast path: pre-convert to bf16, async-staged GEMMs
    bf16_t* XqB = Vtw + MD;  // also reused as AO after gemm_qkv
    bf16_t* XkB = XqB + MD;
    bf16_t* XvB = XkB + MD;
    bf16_t* WqB = XvB + MD;
    bf16_t* WkB = WqB + WD;
    bf16_t* WvB = WkB + WD;
    bf16_t* WoB = WvB + WD;
    bf16_t* AO  = XqB;       // alias: XqB dead after gemm_qkv

    convert_bf16<<<dim3(4096, 7), b256, 0, stream>>>(
        query, key, value, Wq, Wk, Wv, Wo,
        XqB, XkB, XvB, WqB, WkB, WvB, WoB);
    gemm_qkv_b<<<dim3(64, 8, 3), b256, 0, stream>>>(
        XqB, XkB, XvB, WqB, WkB, WvB, bq, bk, bv, Qw, Kw, Vtw);
    flash_attn<<<dim3(8, 64), b512, 0, stream>>>(Qw, Kw, Vtw, AO);
    gemm_out_b<<<dim3(64, 8), b256, 0, stream>>>(AO, WoB, bo, out);
  } else {
    // fallback: fused-convert GEMMs (needs 64 MB ws)
    bf16_t* AO = Vtw + MD;
    gemm_qkv_f<<<dim3(64, 8, 3), b256, 0, stream>>>(
        query, key, value, Wq, Wk, Wv, bq, bk, bv, Qw, Kw, Vtw);
    flash_attn<<<dim3(8, 64), b512, 0, stream>>>(Qw, Kw, Vtw, AO);
    gemm_out_f<<<dim3(64, 8), b256, 0, stream>>>(AO, Wo, bo, out);
  }
}